// Round 13
// baseline (62.564 us; speedup 1.0000x reference)
//
#include <hip/hip_runtime.h>
#include <stdint.h>

#define W 768
#define NPROB (768*768)
#define NB 8
#define NBINS 2048           // coarse bin = (fb>>12)&0x7FF within the [0.5,1) binade
#define CAP 4096
#define TOPK 2048
#define SCORE_THR 0.6f
#define SUBS 32              // sub-blocks per batch
#define SEG (NPROB/SUBS)     // 18432 elems per sub-block
#define PER4 (SEG/4)         // 4608 float4 per sub-block
#define MAGIC 0x4B1DC0DEu

// ws layout (bytes). NOTHING needs pre-init:
//  - hpart/bucket: written before read (intra-kernel handshake orders it)
//  - flags: consumers wait for ==MAGIC (poison 0xAAAAAAAA != MAGIC); reset to 0
//    by the sole consumer via agent-scope stores -> deterministic replays
#define HPART_OFF  0
#define HPART_BYTES (NB*SUBS*NBINS*2)           // 1,048,576 (u16 pairs in u32)
#define BUCKET_OFF (HPART_OFF + HPART_BYTES)
#define BUCKET_BYTES (NB*(size_t)SUBS*SEG*8)    // 37,748,736
#define FLAG_OFF   (BUCKET_OFF + BUCKET_BYTES)
#define FLAG_BYTES (NB*SUBS*4)
#define WS_TOTAL   (FLAG_OFF + FLAG_BYTES)

// valid scores in [0.6,1.0) -> exponent-126 binade; float bits monotone.
__device__ __forceinline__ unsigned score_bin(unsigned fb) {
    return (fb >> 12) & 0x7FFu;
}

// ---- wave-shuffle scans for 1024 threads (1 barrier each) ----
__device__ __forceinline__ unsigned suffix_scan1024(unsigned v, unsigned* wtot, int tid) {
    int lane = tid & 63, wv = tid >> 6;
    unsigned s = v;
    #pragma unroll
    for (int d = 1; d < 64; d <<= 1) {
        unsigned t = __shfl_down(s, d, 64);
        if (lane + d < 64) s += t;
    }
    if (lane == 0) wtot[wv] = s;
    __syncthreads();
    if (tid < 16) {
        unsigned t = wtot[tid];
        #pragma unroll
        for (int d = 1; d < 16; d <<= 1) {
            unsigned u2 = __shfl_down(t, d, 64);
            if (tid + d < 16) t += u2;
        }
        wtot[tid] = t;
    }
    __syncthreads();
    unsigned higher = (wv + 1 < 16) ? wtot[wv + 1] : 0u;
    return s + higher;
}
__device__ __forceinline__ unsigned prefix_scan1024(unsigned v, unsigned* wtot, int tid) {
    int lane = tid & 63, wv = tid >> 6;
    unsigned s = v;
    #pragma unroll
    for (int d = 1; d < 64; d <<= 1) {
        unsigned t = __shfl_up(s, d, 64);
        if (lane >= d) s += t;
    }
    if (lane == 63) wtot[wv] = s;
    __syncthreads();
    if (tid < 16) {
        unsigned t = wtot[tid];
        #pragma unroll
        for (int d = 1; d < 16; d <<= 1) {
            unsigned u2 = __shfl_up(t, d, 64);
            if (tid >= d) t += u2;
        }
        wtot[tid] = t;
    }
    __syncthreads();
    unsigned lower = (wv > 0) ? wtot[wv - 1] : 0u;
    return s + lower;
}

union BigU {
    struct { unsigned lh[NBINS]; unsigned cur[NBINS]; } sc;   // 16 KB (scatter phase)
    unsigned long long keysR[CAP];                            // 32 KB (phases C-F)
    struct {                                                  // 27.7 KB (phases H+)
        unsigned rowcnt[W];
        unsigned rowstart[W + 1];
        unsigned rowcur[W];
        unsigned rowlist[CAP];                                // (x<<12)|rank
        unsigned char state[TOPK];
        int changed;
    } nb;
};

__global__ __launch_bounds__(1024) void fused_kernel(
    const float* __restrict__ probs, const float* __restrict__ dev4,
    unsigned* __restrict__ hpart32, unsigned long long* __restrict__ bucket,
    unsigned* __restrict__ flags, float* __restrict__ out)
{
    __shared__ BigU u;                          // 32 KB
    __shared__ unsigned long long keysS[CAP];   // 32 KB
    __shared__ unsigned p2[NBINS + 1];          // 8.2 KB
    __shared__ unsigned h2[NBINS];              // 8 KB
    __shared__ unsigned wtot[17];
    __shared__ unsigned sj[SUBS];
    __shared__ unsigned basej[SUBS + 1];
    __shared__ unsigned sB0, sbstar, sshift, sfbase;
    const int bid = blockIdx.x, tid = threadIdx.x;
    const int b = bid >> 5, hs = bid & 31;

    // ================= scatter phase (all 256 blocks) =================
    for (int i = tid; i < NBINS; i += 1024) u.sc.lh[i] = 0;
    if (tid == 0) sB0 = 0;
    __syncthreads();
    const float4* p = (const float4*)(probs + (size_t)b * NPROB) + (size_t)hs * PER4;
    for (int i = tid; i < PER4; i += 1024) {
        float4 v = p[i];
        if (v.x >= SCORE_THR) atomicAdd(&u.sc.lh[score_bin(__float_as_uint(v.x))], 1u);
        if (v.y >= SCORE_THR) atomicAdd(&u.sc.lh[score_bin(__float_as_uint(v.y))], 1u);
        if (v.z >= SCORE_THR) atomicAdd(&u.sc.lh[score_bin(__float_as_uint(v.z))], 1u);
        if (v.w >= SCORE_THR) atomicAdd(&u.sc.lh[score_bin(__float_as_uint(v.w))], 1u);
    }
    __syncthreads();
    unsigned c0 = u.sc.lh[2 * tid], c1 = u.sc.lh[2 * tid + 1];
    hpart32[(size_t)(b * SUBS + hs) * (NBINS / 2) + tid] = (c0 & 0xFFFFu) | (c1 << 16);
    unsigned suf = suffix_scan1024(c0 + c1, wtot, tid);
    u.sc.cur[2 * tid] = suf - c0;
    u.sc.cur[2 * tid + 1] = suf - c0 - c1;
    // SAFE local prune: bstar >= B0 := max{B : local pfx[B] >= TOPK}
    unsigned lb0 = 0;
    if (suf >= TOPK) lb0 = 2 * tid;
    if (suf - c0 >= TOPK) lb0 = 2 * tid + 1;
    if (lb0) atomicMax(&sB0, lb0);
    __syncthreads();
    float thrF = __uint_as_float(0x3F000000u | (sB0 << 12));
    if (thrF < SCORE_THR) thrF = SCORE_THR;

    unsigned long long* dst = bucket + (size_t)(b * SUBS + hs) * SEG;
    int base_elem = hs * SEG;
    for (int i = tid; i < PER4; i += 1024) {
        float4 v = p[i];
        int ei = base_elem + i * 4;
        float sv[4] = {v.x, v.y, v.z, v.w};
        #pragma unroll
        for (int c = 0; c < 4; ++c) {
            float s2 = sv[c];
            if (s2 >= thrF) {
                unsigned fb = __float_as_uint(s2);
                unsigned pos = atomicAdd(&u.sc.cur[score_bin(fb)], 1u);
                unsigned idx = (unsigned)(ei + c);
                dst[pos] = ((unsigned long long)fb << 32) | (unsigned)(~idx);
            }
        }
    }
    __syncthreads();

    // ---- handshake: producers publish own flag, finisher (hs==31) waits ----
    if (hs != SUBS - 1) {
        if (tid == 0) {
            __threadfence();
            __hip_atomic_store(&flags[b * SUBS + hs], MAGIC,
                               __ATOMIC_RELEASE, __HIP_MEMORY_SCOPE_AGENT);
        }
        return;
    }
    if (tid < SUBS - 1) {
        while (__hip_atomic_load(&flags[b * SUBS + tid],
                                 __ATOMIC_ACQUIRE, __HIP_MEMORY_SCOPE_AGENT) != MAGIC)
            __builtin_amdgcn_s_sleep(8);
        // reset via agent-scope store (no local dirty line to clobber next replay)
        __hip_atomic_store(&flags[b * SUBS + tid], 0u,
                           __ATOMIC_RELAXED, __HIP_MEMORY_SCOPE_AGENT);
    }
    __syncthreads();
    __threadfence();

    // ================= finish phase (8 blocks, one per batch) =================
    // ---- A: reduce 32 partial hists -> coarse suffix counts; find bstar ----
    c0 = 0; c1 = 0;
    for (int j = 0; j < SUBS; ++j) {
        unsigned pr = hpart32[(size_t)(b * SUBS + j) * (NBINS / 2) + tid];
        c0 += pr & 0xFFFFu;
        c1 += pr >> 16;
    }
    if (tid == 0) sbstar = 0;
    suf = suffix_scan1024(c0 + c1, wtot, tid);
    p2[2 * tid] = suf;
    p2[2 * tid + 1] = suf - c0;
    if (tid == 0) p2[NBINS] = 0;
    __syncthreads();
    {
        int B0 = 2 * tid, B1 = 2 * tid + 1;
        if (p2[B0] >= TOPK && p2[B0 + 1] < TOPK) sbstar = (unsigned)B0;
        if (p2[B1] >= TOPK && p2[B1 + 1] < TOPK) sbstar = (unsigned)B1;
    }
    __syncthreads();
    const unsigned bstar = sbstar;
    const unsigned Tfull = p2[bstar];
    const unsigned T = Tfull < CAP ? Tfull : CAP;
    const int nvalid = (int)(T < TOPK ? T : TOPK);

    // ---- B: per-source-block survivor counts (bins >= bstar) ----
    {
        int j = tid >> 5, lane = tid & 31;
        unsigned s = 0;
        const unsigned* hp = hpart32 + (size_t)(b * SUBS + j) * (NBINS / 2);
        for (unsigned pi = (bstar >> 1) + lane; pi < NBINS / 2; pi += 32) {
            unsigned pr = hp[pi];
            unsigned lo = pr & 0xFFFFu, hi = pr >> 16;
            s += ((2 * pi) >= bstar ? lo : 0u) + hi;
        }
        #pragma unroll
        for (int d = 16; d > 0; d >>= 1) s += __shfl_down(s, d, 32);
        if (lane == 0) sj[j] = s;
    }
    __syncthreads();
    if (tid == 0) {
        unsigned acc = 0;
        for (int j = 0; j < SUBS; ++j) { basej[j] = acc; acc += sj[j]; }
        basej[SUBS] = acc;
        unsigned nb2 = 0x800u - bstar;
        unsigned sft = 0;
        while (((nb2 << 12) >> sft) > (unsigned)NBINS) ++sft;
        sshift = sft;
        sfbase = (0x3F000u + bstar) << 12;
    }
    __syncthreads();
    const unsigned shift = sshift, fbase = sfbase;

    // ---- C: gather survivor keys ----
    for (unsigned i = tid; i < T; i += 1024) {
        int lo = 0, hi = SUBS - 1;
        while (lo < hi) { int mid = (lo + hi + 1) >> 1; if (basej[mid] <= i) lo = mid; else hi = mid - 1; }
        u.keysR[i] = bucket[(size_t)(b * SUBS + lo) * SEG + (i - basej[lo])];
    }
    for (int i = tid; i < NBINS; i += 1024) h2[i] = 0;
    __syncthreads();

    // ---- E: fine histogram + suffix scan ----
    for (unsigned i = tid; i < T; i += 1024) {
        unsigned fb = (unsigned)(u.keysR[i] >> 32);
        atomicAdd(&h2[(fb - fbase) >> shift], 1u);
    }
    __syncthreads();
    {
        unsigned d0 = h2[2 * tid], d1 = h2[2 * tid + 1];
        unsigned sf = suffix_scan1024(d0 + d1, wtot, tid);
        p2[2 * tid] = sf;
        p2[2 * tid + 1] = sf - d0;
        if (tid == 0) p2[NBINS] = 0;
    }
    __syncthreads();
    for (int i = tid; i < NBINS; i += 1024) h2[i] = p2[i + 1];   // cursors
    __syncthreads();

    // ---- F: scatter into fine-bin-grouped keysS ----
    for (unsigned i = tid; i < T; i += 1024) {
        unsigned long long key = u.keysR[i];
        unsigned fb = (unsigned)(key >> 32);
        unsigned pos = atomicAdd(&h2[(fb - fbase) >> shift], 1u);
        keysS[pos] = key;
    }
    __syncthreads();

    // ---- G: exact rank (tiny fine-bin segments; unique keys -> jax order) ----
    unsigned myr[4], myidx[4];
    unsigned long long mykey[4];
    #pragma unroll
    for (int q = 0; q < 4; ++q) {
        unsigned pos = tid + q * 1024;
        myr[q] = 0xFFFFFFFFu;
        mykey[q] = 0; myidx[q] = 0;
        if (pos < T) {
            unsigned long long key = keysS[pos];
            unsigned fb = (unsigned)(key >> 32);
            unsigned B = (fb - fbase) >> shift;
            unsigned st = p2[B + 1], en = p2[B];
            unsigned r = st;
            for (unsigned i = st; i < en; ++i) r += (keysS[i] > key);
            if (r < (unsigned)nvalid) {
                myr[q] = r; mykey[q] = key; myidx[q] = ~(unsigned)key;
            }
        }
    }
    __syncthreads();   // keysR dead; union switches to nb

    // ---- H: row-bucket kept boxes ----
    for (int i = tid; i < W; i += 1024) u.nb.rowcnt[i] = 0;
    for (int i = tid; i < TOPK; i += 1024) u.nb.state[i] = 2;
    __syncthreads();
    #pragma unroll
    for (int q = 0; q < 4; ++q)
        if (myr[q] != 0xFFFFFFFFu) atomicAdd(&u.nb.rowcnt[myidx[q] / W], 1u);
    __syncthreads();
    {
        unsigned c = (tid < W) ? u.nb.rowcnt[tid] : 0u;
        unsigned incl = prefix_scan1024(c, wtot, tid);
        if (tid < W) { u.nb.rowstart[tid + 1] = incl; u.nb.rowcur[tid] = incl - c; }
        if (tid == 0) u.nb.rowstart[0] = 0;
    }
    __syncthreads();
    #pragma unroll
    for (int q = 0; q < 4; ++q)
        if (myr[q] != 0xFFFFFFFFu) {
            unsigned y = myidx[q] / W, x = myidx[q] % W;
            unsigned pos = atomicAdd(&u.nb.rowcur[y], 1u);
            u.nb.rowlist[pos] = (x << 12) | myr[q];
        }
    __syncthreads();

    // ---- I: neighbor discovery in LDS (rows y-1..y+1, |dx|<=1, earlier rank) ----
    unsigned long long l0[4] = {0,0,0,0}, l1[4] = {0,0,0,0};
    int nc[4] = {0,0,0,0};
    #pragma unroll
    for (int q = 0; q < 4; ++q) {
        if (myr[q] != 0xFFFFFFFFu) {
            unsigned y = myidx[q] / W, x = myidx[q] % W;
            int c2 = 0;
            unsigned long long a0 = 0, a1 = 0;
            #pragma unroll
            for (int dy = -1; dy <= 1; ++dy) {
                unsigned yy = y + (unsigned)dy;
                if (yy < (unsigned)W) {
                    unsigned s0 = u.nb.rowstart[yy], e0 = u.nb.rowstart[yy + 1];
                    for (unsigned i = s0; i < e0; ++i) {
                        unsigned e = u.nb.rowlist[i];
                        unsigned xx = e >> 12, rr = e & 0xFFFu;
                        if ((xx - x + 1u) <= 2u && rr < myr[q]) {
                            if (c2 < 4)      a0 |= (unsigned long long)rr << (c2 * 16);
                            else if (c2 < 8) a1 |= (unsigned long long)rr << ((c2 - 4) * 16);
                            c2++;
                        }
                    }
                }
            }
            if (c2 > 8) c2 = 8;
            l0[q] = a0; l1[q] = a1; nc[q] = c2;
            u.nb.state[myr[q]] = (c2 == 0) ? 1 : 0;
        }
    }
    __syncthreads();

    // ---- J: monotone fixpoint == sequential greedy NMS ----
    while (true) {
        if (tid == 0) u.nb.changed = 0;
        __syncthreads();
        bool ch = false;
        #pragma unroll
        for (int q = 0; q < 4; ++q) {
            if (myr[q] != 0xFFFFFFFFu && u.nb.state[myr[q]] == 0) {
                bool anyK = false, anyU = false;
                int c = nc[q];
                #pragma unroll
                for (int l = 0; l < 8; ++l) {
                    if (l < c) {
                        unsigned rr = (l < 4)
                            ? (unsigned)((l0[q] >> (l * 16)) & 0xFFFFu)
                            : (unsigned)((l1[q] >> ((l - 4) * 16)) & 0xFFFFu);
                        unsigned char st = u.nb.state[rr];
                        anyK |= (st == 1);
                        anyU |= (st == 0);
                    }
                }
                if (anyK)      { u.nb.state[myr[q]] = 2; ch = true; }
                else if (!anyU){ u.nb.state[myr[q]] = 1; ch = true; }
            }
        }
        if (ch) u.nb.changed = 1;
        __syncthreads();
        if (u.nb.changed == 0) break;
        __syncthreads();
    }

    // ---- K: refine + write ----
    for (int r = nvalid + tid; r < TOPK; r += 1024) {
        float* op = out + ((size_t)b * TOPK + r) * 5;
        op[0] = 0.f; op[1] = 0.f; op[2] = 0.f; op[3] = 0.f; op[4] = 0.f;
    }
    #pragma unroll
    for (int q = 0; q < 4; ++q) {
        if (myr[q] != 0xFFFFFFFFu) {
            unsigned r = myr[q];
            float o0 = 0.f, o1 = 0.f, o2 = 0.f, o3 = 0.f, o4 = 0.f;
            if (u.nb.state[r] == 1) {
                unsigned idx = myidx[q];
                float sc = __uint_as_float((unsigned)(mykey[q] >> 32));
                int y = (int)(idx / W), x = (int)(idx % W);
                const float4 d = ((const float4*)dev4)[(size_t)b * NPROB + idx];
                float b0 = (float)(4 * y + 2);
                float b1 = (float)(4 * x + 2);
                float b2 = (float)(4 * y + 24);
                float b3 = (float)(4 * x + 24);
                float r0 = b0 + d.x * 22.0f;
                float r1 = b1 + d.y * 22.0f;
                float r2 = b2 + d.z * 22.0f;
                float r3 = b3 + d.w * 22.0f;
                float rh = r2 - r0, rw = r3 - r1;
                float len = fmaxf(rh, rw);
                float c0v = r0 + rh * 0.5f, c1v = r1 + rw * 0.5f;
                float u0 = c0v - 0.5f * len, u1 = c1v - 0.5f * len;
                float v0 = u0 + len, v1 = u1 + len;
                o0 = fminf(fmaxf(u0, 1.0f), 3095.0f);
                o1 = fminf(fmaxf(u1, 1.0f), 3095.0f);
                o2 = fminf(fmaxf(v0, 1.0f), 3095.0f);
                o3 = fminf(fmaxf(v1, 1.0f), 3095.0f);
                o4 = sc;
            }
            float* op = out + ((size_t)b * TOPK + r) * 5;
            op[0] = o0; op[1] = o1; op[2] = o2; op[3] = o3; op[4] = o4;
        }
    }
}

extern "C" void kernel_launch(void* const* d_in, const int* in_sizes, int n_in,
                              void* d_out, int out_size, void* d_ws, size_t ws_size,
                              hipStream_t stream) {
    (void)in_sizes; (void)n_in; (void)out_size;
    if (ws_size < (size_t)WS_TOTAL) return;

    const float* probs = (const float*)d_in[0];
    const float* devs  = (const float*)d_in[1];
    float* out = (float*)d_out;
    char* ws = (char*)d_ws;

    unsigned* hpart32 = (unsigned*)(ws + HPART_OFF);
    unsigned long long* bucket = (unsigned long long*)(ws + BUCKET_OFF);
    unsigned* flags = (unsigned*)(ws + FLAG_OFF);

    fused_kernel<<<NB * SUBS, 1024, 0, stream>>>(probs, devs, hpart32, bucket, flags, out);
}

// Round 14
// 35.392 us; speedup vs baseline: 1.7678x; 1.7678x over previous
//
#include <hip/hip_runtime.h>
#include <stdint.h>

#define W 768
#define NPROB (768*768)
#define NB 8
#define NBINS 2048           // coarse bin = (fb>>12)&0x7FF within the [0.5,1) binade
#define CAP 4096
#define TOPK 2048
#define SCORE_THR 0.6f
#define SUBS 32              // K1 blocks per batch
#define SEG (NPROB/SUBS)     // 18432 elems per K1 block
#define PER4 (SEG/4)         // 4608 float4 per K1 block

// ws layout (bytes). NOTHING needs pre-init: bucket/hpart written by K1
// before K2 reads (stream order).
#define HPART_OFF  0
#define HPART_BYTES (NB*SUBS*NBINS*2)           // 1,048,576 (u16 pairs in u32)
#define BUCKET_OFF (HPART_OFF + HPART_BYTES)
#define BUCKET_BYTES (NB*(size_t)SUBS*SEG*8)    // 37,748,736
#define WS_TOTAL   (BUCKET_OFF + BUCKET_BYTES)

// valid scores in [0.6,1.0) -> exponent-126 binade; float bits monotone.
__device__ __forceinline__ unsigned score_bin(unsigned fb) {
    return (fb >> 12) & 0x7FFu;
}

// ---- wave-shuffle scans for 1024 threads (1 barrier each) ----
__device__ __forceinline__ unsigned suffix_scan1024(unsigned v, unsigned* wtot, int tid) {
    int lane = tid & 63, wv = tid >> 6;
    unsigned s = v;
    #pragma unroll
    for (int d = 1; d < 64; d <<= 1) {
        unsigned t = __shfl_down(s, d, 64);
        if (lane + d < 64) s += t;
    }
    if (lane == 0) wtot[wv] = s;
    __syncthreads();
    if (tid < 16) {
        unsigned t = wtot[tid];
        #pragma unroll
        for (int d = 1; d < 16; d <<= 1) {
            unsigned u2 = __shfl_down(t, d, 64);
            if (tid + d < 16) t += u2;
        }
        wtot[tid] = t;
    }
    __syncthreads();
    unsigned higher = (wv + 1 < 16) ? wtot[wv + 1] : 0u;
    return s + higher;
}
__device__ __forceinline__ unsigned prefix_scan1024(unsigned v, unsigned* wtot, int tid) {
    int lane = tid & 63, wv = tid >> 6;
    unsigned s = v;
    #pragma unroll
    for (int d = 1; d < 64; d <<= 1) {
        unsigned t = __shfl_up(s, d, 64);
        if (lane >= d) s += t;
    }
    if (lane == 63) wtot[wv] = s;
    __syncthreads();
    if (tid < 16) {
        unsigned t = wtot[tid];
        #pragma unroll
        for (int d = 1; d < 16; d <<= 1) {
            unsigned u2 = __shfl_up(t, d, 64);
            if (tid >= d) t += u2;
        }
        wtot[tid] = t;
    }
    __syncthreads();
    unsigned lower = (wv > 0) ? wtot[wv - 1] : 0u;
    return s + lower;
}

// K1: per-block counting sort with SAFE local prune (r12 logic, 1024 threads
// for 16 waves/CU of latency hiding on the streaming read).
__global__ __launch_bounds__(1024) void scatter_kernel(
    const float* __restrict__ probs, unsigned* __restrict__ hpart32,
    unsigned long long* __restrict__ bucket)
{
    __shared__ unsigned lh[NBINS];     // 8 KB
    __shared__ unsigned cur[NBINS];    // 8 KB
    __shared__ unsigned wtot[17];
    __shared__ unsigned sB0;
    const int b = blockIdx.y, hs = blockIdx.x, tid = threadIdx.x;

    for (int i = tid; i < NBINS; i += 1024) lh[i] = 0;
    if (tid == 0) sB0 = 0;
    __syncthreads();
    const float4* p = (const float4*)(probs + (size_t)b * NPROB) + (size_t)hs * PER4;
    for (int i = tid; i < PER4; i += 1024) {
        float4 v = p[i];
        if (v.x >= SCORE_THR) atomicAdd(&lh[score_bin(__float_as_uint(v.x))], 1u);
        if (v.y >= SCORE_THR) atomicAdd(&lh[score_bin(__float_as_uint(v.y))], 1u);
        if (v.z >= SCORE_THR) atomicAdd(&lh[score_bin(__float_as_uint(v.z))], 1u);
        if (v.w >= SCORE_THR) atomicAdd(&lh[score_bin(__float_as_uint(v.w))], 1u);
    }
    __syncthreads();
    unsigned c0 = lh[2 * tid], c1 = lh[2 * tid + 1];
    hpart32[(size_t)(b * SUBS + hs) * (NBINS / 2) + tid] = (c0 & 0xFFFFu) | (c1 << 16);
    unsigned suf = suffix_scan1024(c0 + c1, wtot, tid);
    cur[2 * tid] = suf - c0;
    cur[2 * tid + 1] = suf - c0 - c1;
    // SAFE local prune: bstar >= B0 := max{B : local pfx[B] >= TOPK}
    unsigned lb0 = 0;
    if (suf >= TOPK) lb0 = 2 * tid;
    if (suf - c0 >= TOPK) lb0 = 2 * tid + 1;
    if (lb0) atomicMax(&sB0, lb0);
    __syncthreads();
    float thrF = __uint_as_float(0x3F000000u | (sB0 << 12));
    if (thrF < SCORE_THR) thrF = SCORE_THR;

    unsigned long long* dst = bucket + (size_t)(b * SUBS + hs) * SEG;
    int base_elem = hs * SEG;
    for (int i = tid; i < PER4; i += 1024) {
        float4 v = p[i];
        int ei = base_elem + i * 4;
        float sv[4] = {v.x, v.y, v.z, v.w};
        #pragma unroll
        for (int c = 0; c < 4; ++c) {
            float s2 = sv[c];
            if (s2 >= thrF) {
                unsigned fb = __float_as_uint(s2);
                unsigned pos = atomicAdd(&cur[score_bin(fb)], 1u);
                unsigned idx = (unsigned)(ei + c);
                dst[pos] = ((unsigned long long)fb << 32) | (unsigned)(~idx);
            }
        }
    }
}

// K2: one block per batch, ALL-LDS after the gathers (r12 structure).
union UA {
    unsigned long long keysR[CAP];                   // 32 KB  (phases C-F)
    struct {                                         // 27.7 KB (phases H+)
        unsigned rowcnt[W];
        unsigned rowstart[W + 1];
        unsigned rowcur[W];
        unsigned rowlist[CAP];                       // (x<<12)|rank
        unsigned char state[TOPK];
        int changed;
    } nb;
};

__global__ __launch_bounds__(1024) void finish_kernel(
    const float* __restrict__ dev4, const unsigned* __restrict__ hpart32,
    const unsigned long long* __restrict__ bucket, float* __restrict__ out)
{
    __shared__ unsigned p2[NBINS + 1];
    __shared__ unsigned h2[NBINS];
    __shared__ unsigned wtot[17];
    __shared__ unsigned long long keysS[CAP];
    __shared__ UA u;
    __shared__ unsigned sj[SUBS];
    __shared__ unsigned basej[SUBS + 1];
    __shared__ unsigned sbstar, sshift, sfbase;
    const int b = blockIdx.x, tid = threadIdx.x;

    // ---- A: reduce 32 partial hists (unrolled for outstanding loads) ----
    unsigned c0 = 0, c1 = 0;
    {
        const unsigned* hp = hpart32 + (size_t)b * SUBS * (NBINS / 2) + tid;
        unsigned pr[SUBS];
        #pragma unroll
        for (int j = 0; j < SUBS; ++j) pr[j] = hp[(size_t)j * (NBINS / 2)];
        #pragma unroll
        for (int j = 0; j < SUBS; ++j) { c0 += pr[j] & 0xFFFFu; c1 += pr[j] >> 16; }
    }
    if (tid == 0) sbstar = 0;
    unsigned suf = suffix_scan1024(c0 + c1, wtot, tid);
    p2[2 * tid] = suf;
    p2[2 * tid + 1] = suf - c0;
    if (tid == 0) p2[NBINS] = 0;
    __syncthreads();
    {
        int B0 = 2 * tid, B1 = 2 * tid + 1;
        if (p2[B0] >= TOPK && p2[B0 + 1] < TOPK) sbstar = (unsigned)B0;
        if (p2[B1] >= TOPK && p2[B1 + 1] < TOPK) sbstar = (unsigned)B1;
    }
    __syncthreads();
    const unsigned bstar = sbstar;
    const unsigned Tfull = p2[bstar];
    const unsigned T = Tfull < CAP ? Tfull : CAP;
    const int nvalid = (int)(T < TOPK ? T : TOPK);

    // ---- B: per-source-block survivor counts (bins >= bstar) ----
    {
        int j = tid >> 5, lane = tid & 31;
        unsigned s = 0;
        const unsigned* hp = hpart32 + (size_t)(b * SUBS + j) * (NBINS / 2);
        for (unsigned pi = (bstar >> 1) + lane; pi < NBINS / 2; pi += 32) {
            unsigned pr = hp[pi];
            unsigned lo = pr & 0xFFFFu, hi = pr >> 16;
            s += ((2 * pi) >= bstar ? lo : 0u) + hi;
        }
        #pragma unroll
        for (int d = 16; d > 0; d >>= 1) s += __shfl_down(s, d, 32);
        if (lane == 0) sj[j] = s;
    }
    __syncthreads();
    if (tid == 0) {
        unsigned acc = 0;
        for (int j = 0; j < SUBS; ++j) { basej[j] = acc; acc += sj[j]; }
        basej[SUBS] = acc;
        unsigned nb2 = 0x800u - bstar;
        unsigned sft = 0;
        while (((nb2 << 12) >> sft) > (unsigned)NBINS) ++sft;
        sshift = sft;
        sfbase = (0x3F000u + bstar) << 12;
    }
    __syncthreads();
    const unsigned shift = sshift, fbase = sfbase;

    // ---- C: gather survivor keys ----
    for (unsigned i = tid; i < T; i += 1024) {
        int lo = 0, hi = SUBS - 1;
        while (lo < hi) { int mid = (lo + hi + 1) >> 1; if (basej[mid] <= i) lo = mid; else hi = mid - 1; }
        u.keysR[i] = bucket[(size_t)(b * SUBS + lo) * SEG + (i - basej[lo])];
    }
    for (int i = tid; i < NBINS; i += 1024) h2[i] = 0;
    __syncthreads();

    // ---- E: fine histogram + suffix scan ----
    for (unsigned i = tid; i < T; i += 1024) {
        unsigned fb = (unsigned)(u.keysR[i] >> 32);
        atomicAdd(&h2[(fb - fbase) >> shift], 1u);
    }
    __syncthreads();
    {
        unsigned d0 = h2[2 * tid], d1 = h2[2 * tid + 1];
        unsigned sf = suffix_scan1024(d0 + d1, wtot, tid);
        p2[2 * tid] = sf;
        p2[2 * tid + 1] = sf - d0;
        if (tid == 0) p2[NBINS] = 0;
    }
    __syncthreads();
    for (int i = tid; i < NBINS; i += 1024) h2[i] = p2[i + 1];   // cursors
    __syncthreads();

    // ---- F: scatter into fine-bin-grouped keysS ----
    for (unsigned i = tid; i < T; i += 1024) {
        unsigned long long key = u.keysR[i];
        unsigned fb = (unsigned)(key >> 32);
        unsigned pos = atomicAdd(&h2[(fb - fbase) >> shift], 1u);
        keysS[pos] = key;
    }
    __syncthreads();

    // ---- G: exact rank (tiny fine-bin segments; unique keys -> jax order) ----
    unsigned myr[4], myidx[4];
    unsigned long long mykey[4];
    #pragma unroll
    for (int q = 0; q < 4; ++q) {
        unsigned pos = tid + q * 1024;
        myr[q] = 0xFFFFFFFFu;
        mykey[q] = 0; myidx[q] = 0;
        if (pos < T) {
            unsigned long long key = keysS[pos];
            unsigned fb = (unsigned)(key >> 32);
            unsigned B = (fb - fbase) >> shift;
            unsigned st = p2[B + 1], en = p2[B];
            unsigned r = st;
            for (unsigned i = st; i < en; ++i) r += (keysS[i] > key);
            if (r < (unsigned)nvalid) {
                myr[q] = r; mykey[q] = key; myidx[q] = ~(unsigned)key;
            }
        }
    }
    __syncthreads();   // keysR dead; union switches to nb

    // ---- H: row-bucket kept boxes ----
    for (int i = tid; i < W; i += 1024) u.nb.rowcnt[i] = 0;
    for (int i = tid; i < TOPK; i += 1024) u.nb.state[i] = 2;
    __syncthreads();
    #pragma unroll
    for (int q = 0; q < 4; ++q)
        if (myr[q] != 0xFFFFFFFFu) atomicAdd(&u.nb.rowcnt[myidx[q] / W], 1u);
    __syncthreads();
    {
        unsigned c = (tid < W) ? u.nb.rowcnt[tid] : 0u;
        unsigned incl = prefix_scan1024(c, wtot, tid);
        if (tid < W) { u.nb.rowstart[tid + 1] = incl; u.nb.rowcur[tid] = incl - c; }
        if (tid == 0) u.nb.rowstart[0] = 0;
    }
    __syncthreads();
    #pragma unroll
    for (int q = 0; q < 4; ++q)
        if (myr[q] != 0xFFFFFFFFu) {
            unsigned y = myidx[q] / W, x = myidx[q] % W;
            unsigned pos = atomicAdd(&u.nb.rowcur[y], 1u);
            u.nb.rowlist[pos] = (x << 12) | myr[q];
        }
    __syncthreads();

    // ---- I: neighbor discovery in LDS (rows y-1..y+1, |dx|<=1, earlier rank) ----
    unsigned long long l0[4] = {0,0,0,0}, l1[4] = {0,0,0,0};
    int nc[4] = {0,0,0,0};
    #pragma unroll
    for (int q = 0; q < 4; ++q) {
        if (myr[q] != 0xFFFFFFFFu) {
            unsigned y = myidx[q] / W, x = myidx[q] % W;
            int c2 = 0;
            unsigned long long a0 = 0, a1 = 0;
            #pragma unroll
            for (int dy = -1; dy <= 1; ++dy) {
                unsigned yy = y + (unsigned)dy;
                if (yy < (unsigned)W) {
                    unsigned s0 = u.nb.rowstart[yy], e0 = u.nb.rowstart[yy + 1];
                    for (unsigned i = s0; i < e0; ++i) {
                        unsigned e = u.nb.rowlist[i];
                        unsigned xx = e >> 12, rr = e & 0xFFFu;
                        if ((xx - x + 1u) <= 2u && rr < myr[q]) {
                            if (c2 < 4)      a0 |= (unsigned long long)rr << (c2 * 16);
                            else if (c2 < 8) a1 |= (unsigned long long)rr << ((c2 - 4) * 16);
                            c2++;
                        }
                    }
                }
            }
            if (c2 > 8) c2 = 8;
            l0[q] = a0; l1[q] = a1; nc[q] = c2;
            u.nb.state[myr[q]] = (c2 == 0) ? 1 : 0;
        }
    }
    __syncthreads();

    // ---- J: monotone fixpoint == sequential greedy NMS ----
    while (true) {
        if (tid == 0) u.nb.changed = 0;
        __syncthreads();
        bool ch = false;
        #pragma unroll
        for (int q = 0; q < 4; ++q) {
            if (myr[q] != 0xFFFFFFFFu && u.nb.state[myr[q]] == 0) {
                bool anyK = false, anyU = false;
                int c = nc[q];
                #pragma unroll
                for (int l = 0; l < 8; ++l) {
                    if (l < c) {
                        unsigned rr = (l < 4)
                            ? (unsigned)((l0[q] >> (l * 16)) & 0xFFFFu)
                            : (unsigned)((l1[q] >> ((l - 4) * 16)) & 0xFFFFu);
                        unsigned char st = u.nb.state[rr];
                        anyK |= (st == 1);
                        anyU |= (st == 0);
                    }
                }
                if (anyK)      { u.nb.state[myr[q]] = 2; ch = true; }
                else if (!anyU){ u.nb.state[myr[q]] = 1; ch = true; }
            }
        }
        if (ch) u.nb.changed = 1;
        __syncthreads();
        if (u.nb.changed == 0) break;
        __syncthreads();
    }

    // ---- K: refine + write ----
    for (int r = nvalid + tid; r < TOPK; r += 1024) {
        float* op = out + ((size_t)b * TOPK + r) * 5;
        op[0] = 0.f; op[1] = 0.f; op[2] = 0.f; op[3] = 0.f; op[4] = 0.f;
    }
    #pragma unroll
    for (int q = 0; q < 4; ++q) {
        if (myr[q] != 0xFFFFFFFFu) {
            unsigned r = myr[q];
            float o0 = 0.f, o1 = 0.f, o2 = 0.f, o3 = 0.f, o4 = 0.f;
            if (u.nb.state[r] == 1) {
                unsigned idx = myidx[q];
                float sc = __uint_as_float((unsigned)(mykey[q] >> 32));
                int y = (int)(idx / W), x = (int)(idx % W);
                const float4 d = ((const float4*)dev4)[(size_t)b * NPROB + idx];
                float b0 = (float)(4 * y + 2);
                float b1 = (float)(4 * x + 2);
                float b2 = (float)(4 * y + 24);
                float b3 = (float)(4 * x + 24);
                float r0 = b0 + d.x * 22.0f;
                float r1 = b1 + d.y * 22.0f;
                float r2 = b2 + d.z * 22.0f;
                float r3 = b3 + d.w * 22.0f;
                float rh = r2 - r0, rw = r3 - r1;
                float len = fmaxf(rh, rw);
                float c0v = r0 + rh * 0.5f, c1v = r1 + rw * 0.5f;
                float u0 = c0v - 0.5f * len, u1 = c1v - 0.5f * len;
                float v0 = u0 + len, v1 = u1 + len;
                o0 = fminf(fmaxf(u0, 1.0f), 3095.0f);
                o1 = fminf(fmaxf(u1, 1.0f), 3095.0f);
                o2 = fminf(fmaxf(v0, 1.0f), 3095.0f);
                o3 = fminf(fmaxf(v1, 1.0f), 3095.0f);
                o4 = sc;
            }
            float* op = out + ((size_t)b * TOPK + r) * 5;
            op[0] = o0; op[1] = o1; op[2] = o2; op[3] = o3; op[4] = o4;
        }
    }
}

extern "C" void kernel_launch(void* const* d_in, const int* in_sizes, int n_in,
                              void* d_out, int out_size, void* d_ws, size_t ws_size,
                              hipStream_t stream) {
    (void)in_sizes; (void)n_in; (void)out_size;
    if (ws_size < (size_t)WS_TOTAL) return;

    const float* probs = (const float*)d_in[0];
    const float* devs  = (const float*)d_in[1];
    float* out = (float*)d_out;
    char* ws = (char*)d_ws;

    unsigned* hpart32 = (unsigned*)(ws + HPART_OFF);
    unsigned long long* bucket = (unsigned long long*)(ws + BUCKET_OFF);

    scatter_kernel<<<dim3(SUBS, NB), 1024, 0, stream>>>(probs, hpart32, bucket);
    finish_kernel<<<NB, 1024, 0, stream>>>(devs, hpart32, bucket, out);
}